// Round 2
// baseline (120.535 us; speedup 1.0000x reference)
//
#include <hip/hip_runtime.h>
#include <hip/hip_bf16.h>

#define BN 262144
#define LNUM 15

// out[o] = bias[o] + sum_i in[i] * W[i][o]   (W row-major 8x8, f32)
__device__ __forceinline__ void matvec8(const float in[8],
                                        const float* __restrict__ W,
                                        const float* __restrict__ b,
                                        float out[8]) {
#pragma unroll
    for (int o = 0; o < 8; ++o) out[o] = b[o];
#pragma unroll
    for (int ii = 0; ii < 8; ++ii) {
        float xv = in[ii];
#pragma unroll
        for (int o = 0; o < 8; ++o) out[o] = fmaf(xv, W[ii * 8 + o], out[o]);
    }
}

__device__ __forceinline__ void lrelu8(float v[8]) {
#pragma unroll
    for (int o = 0; o < 8; ++o) v[o] = fmaxf(v[o], 0.01f * v[o]);
}

__device__ __forceinline__ void mlp8(const float in[8],
                                     const float* __restrict__ Wi, const float* __restrict__ bi,
                                     const float* __restrict__ Wh, const float* __restrict__ bh,
                                     const float* __restrict__ Wo, const float* __restrict__ bo,
                                     float out[8]) {
    float h[8], g[8];
    matvec8(in, Wi, bi, h);
    lrelu8(h);
#pragma unroll
    for (int j = 0; j < 3; ++j) {
        matvec8(h, Wh + j * 64, bh + j * 8, g);
        lrelu8(g);
#pragma unroll
        for (int k = 0; k < 8; ++k) h[k] = g[k];
    }
    matvec8(h, Wo, bo, out);
}

extern "C" __global__ void __launch_bounds__(256) flow_fwd(
    const float* __restrict__ z,
    const float* __restrict__ Wi, const float* __restrict__ bi,
    const float* __restrict__ Wh, const float* __restrict__ bh,
    const float* __restrict__ Wo, const float* __restrict__ bo,
    const int* __restrict__ perms,
    float* __restrict__ outy, float* __restrict__ outld) {
    // per-thread private 16-float vector slot, stride 17 (coprime with 32 banks)
    __shared__ float xs[256 * 17];
    const int t = threadIdx.x;
    const long i = (long)blockIdx.x * 256 + t;

    float x[16];
    {
        const float4* zp = reinterpret_cast<const float4*>(z + i * 16);
        float4 a0 = zp[0], a1 = zp[1], a2 = zp[2], a3 = zp[3];
        x[0] = a0.x;  x[1] = a0.y;  x[2] = a0.z;  x[3] = a0.w;
        x[4] = a1.x;  x[5] = a1.y;  x[6] = a1.z;  x[7] = a1.w;
        x[8] = a2.x;  x[9] = a2.y;  x[10] = a2.z; x[11] = a2.w;
        x[12] = a3.x; x[13] = a3.y; x[14] = a3.z; x[15] = a3.w;
    }
    float ld = 0.f;
    float* myx = &xs[t * 17];

    for (int l = 0; l < LNUM; ++l) {
        float sv[8], bv[8];
        const int lm0 = l * 2, lm1 = l * 2 + 1;
        // net 0: log_s ; net 1: b   (uniform scalar offsets per layer)
        mlp8(x, Wi + lm0 * 64, bi + lm0 * 8, Wh + lm0 * 192, bh + lm0 * 24,
             Wo + lm0 * 64, bo + lm0 * 8, sv);
        mlp8(x, Wi + lm1 * 64, bi + lm1 * 8, Wh + lm1 * 192, bh + lm1 * 24,
             Wo + lm1 * 64, bo + lm1 * 8, bv);
#pragma unroll
        for (int k = 0; k < 8; ++k) {
            float s = fminf(fmaxf(sv[k], -5.f), 5.f);
            ld += s;
            x[8 + k] = (__expf(s) + 1e-6f) * x[8 + k] + bv[k];
        }
        // column permutation via private LDS slot (runtime uniform indices)
#pragma unroll
        for (int p = 0; p < 16; ++p) myx[p] = x[p];
        const int* pl = perms + l * 16;
#pragma unroll
        for (int j = 0; j < 16; ++j) x[j] = myx[pl[j]];
    }

    float* yrow = outy + i * 16;
    float4 o0, o1, o2, o3;
    o0.x = x[0];  o0.y = x[1];  o0.z = x[2];  o0.w = x[3];
    o1.x = x[4];  o1.y = x[5];  o1.z = x[6];  o1.w = x[7];
    o2.x = x[8];  o2.y = x[9];  o2.z = x[10]; o2.w = x[11];
    o3.x = x[12]; o3.y = x[13]; o3.z = x[14]; o3.w = x[15];
    reinterpret_cast<float4*>(yrow)[0] = o0;
    reinterpret_cast<float4*>(yrow)[1] = o1;
    reinterpret_cast<float4*>(yrow)[2] = o2;
    reinterpret_cast<float4*>(yrow)[3] = o3;
    outld[i] = ld;
}

extern "C" void kernel_launch(void* const* d_in, const int* in_sizes, int n_in,
                              void* d_out, int out_size, void* d_ws, size_t ws_size,
                              hipStream_t stream) {
    const float* z = (const float*)d_in[0];
    const float* Wi = (const float*)d_in[1];
    const float* bi = (const float*)d_in[2];
    const float* Wh = (const float*)d_in[3];
    const float* bh = (const float*)d_in[4];
    const float* Wo = (const float*)d_in[5];
    const float* bo = (const float*)d_in[6];
    const int* perms = (const int*)d_in[7];
    float* out = (float*)d_out;

    dim3 grid(BN / 256), block(256);
    hipLaunchKernelGGL(flow_fwd, grid, block, 0, stream,
                       z, Wi, bi, Wh, bh, Wo, bo, perms, out, out + (size_t)BN * 16);
}